// Round 10
// baseline (85.550 us; speedup 1.0000x reference)
//
#include <hip/hip_runtime.h>
#include <hip/hip_bf16.h>

#define D 128            // D_IN == D_OUT == 128
#define RPB 8            // rows per bucket
#define NBMAX 1280       // max buckets (N<=10240)
#define EPB 2048         // edges per block in hist/place
#define CAP 1024         // staged edges per bucket (mean 512, ~22 sigma)
#define EPS 1e-8f

typedef unsigned int uint32;
typedef unsigned short uint16;

__device__ __forceinline__ uint32 f2bf_rne(float f) {
    uint32 u = __float_as_uint(f);
    return (u + 0x7fffu + ((u >> 16) & 1u)) >> 16;   // round-nearest-even
}
__device__ __forceinline__ float bfl(uint32 u) { return __uint_as_float(u << 16); }
__device__ __forceinline__ float bfh(uint32 u) { return __uint_as_float(u & 0xffff0000u); }

// -------- prep: W transpose+bf16 pack + bucket histogram (chunked) ----------
// WT[k2][f] packs (W[f][2k2], W[f][2k2+1])

__global__ __launch_bounds__(256) void k_prep_all(
        const int* __restrict__ ei,
        const float* __restrict__ Wm, const float* __restrict__ Wu,
        uint32* __restrict__ WTmb, uint32* __restrict__ WTub,
        int* __restrict__ bhist, int E_, int NB) {
    __shared__ int h[NBMAX];
    const int i = blockIdx.x * 256 + threadIdx.x;

    if (i < 64 * D) {
        int k2 = i >> 7, f = i & 127;
        WTmb[i] = f2bf_rne(Wm[f * D + 2 * k2]) | (f2bf_rne(Wm[f * D + 2 * k2 + 1]) << 16);
        WTub[i] = f2bf_rne(Wu[f * D + 2 * k2]) | (f2bf_rne(Wu[f * D + 2 * k2 + 1]) << 16);
    }

    int base = blockIdx.x * EPB;
    if (base < E_) {
        for (int b = threadIdx.x; b < NB; b += 256) h[b] = 0;
        __syncthreads();
        int hi2 = min(base + EPB, E_);
        for (int e = base + threadIdx.x; e < hi2; e += 256)
            atomicAdd(&h[ei[e] >> 3], 1);
        __syncthreads();
        for (int b = threadIdx.x; b < NB; b += 256)
            if (h[b]) atomicAdd(&bhist[b], h[b]);
    }
}

// ---------------- scan ----------------

__global__ void k_scan(const int* __restrict__ deg, int* __restrict__ starts, int N_) {
    __shared__ int part[1024];
    int t = threadIdx.x;
    int chunk = (N_ + 1023) / 1024;
    int s = t * chunk;
    int e = min(N_, s + chunk);
    int sum = 0;
    for (int i = s; i < e; ++i) sum += deg[i];
    part[t] = sum;
    __syncthreads();
    for (int off = 1; off < 1024; off <<= 1) {
        int u = (t >= off) ? part[t - off] : 0;
        __syncthreads();
        part[t] += u;
        __syncthreads();
    }
    int run = part[t] - sum;
    for (int i = s; i < e; ++i) { starts[i] = run; run += deg[i]; }
    if (t == 1023) starts[N_] = part[1023];
}

// ---------------- place: block-local counting sort by bucket ----------------

__global__ __launch_bounds__(256) void k_bplace(
        const int* __restrict__ ei, const int* __restrict__ bstart,
        int* __restrict__ bcur, uint32* __restrict__ eb, int E_, int NB) {
    __shared__ int h[NBMAX];
    __shared__ int off[NBMAX];
    __shared__ int bias[NBMAX];
    __shared__ uint32 stg[EPB];

    const int tid = threadIdx.x;
    const int base = blockIdx.x * EPB;
    const int nE = min(EPB, E_ - base);

    for (int i = tid; i < NB; i += 256) h[i] = 0;
    __syncthreads();

    for (int i = tid; i < nE; i += 256)
        atomicAdd(&h[ei[base + i] >> 3], 1);
    __syncthreads();

    if (tid < 64) {
        int b0 = tid * 20;
        int loc[20];
        int lsum = 0;
        #pragma unroll
        for (int j = 0; j < 20; ++j) {
            int b = b0 + j;
            int v = (b < NB) ? h[b] : 0;
            loc[j] = lsum;
            lsum += v;
        }
        int run = lsum;
        #pragma unroll
        for (int o = 1; o < 64; o <<= 1) {
            int u = __shfl_up(run, o);
            if (tid >= o) run += u;
        }
        int excl = run - lsum;
        #pragma unroll
        for (int j = 0; j < 20; ++j) {
            int b = b0 + j;
            if (b < NB) off[b] = excl + loc[j];
        }
    }
    __syncthreads();

    for (int b = tid; b < NB; b += 256) {
        int c = h[b];
        if (c) {
            int g = atomicAdd(&bcur[b], c);
            bias[b] = (bstart[b] + g) - off[b];
        }
    }
    __syncthreads();

    for (int i = tid; i < nE; i += 256) {
        int r = ei[base + i];
        int c = ei[E_ + base + i];
        int b = r >> 3;
        int p = atomicAdd(&off[b], 1);
        stg[p] = ((uint32)r << 16) | (uint32)c;
    }
    __syncthreads();

    for (int i = tid; i < nE; i += 256) {
        uint32 v = stg[i];
        int b = v >> 19;                  // row = v>>16, bucket = row>>3
        eb[bias[b] + i] = v;
    }
}

// ---------------- fused: row sort + f32 register gather + k-split matvecs ----
// one block per bucket (8 rows); 256 threads = 4 waves.
// gather: wave owns 2 rows.  matvec: wave owns a 32-wide k-slice of ALL rows.

__global__ __launch_bounds__(256) void k_fused(
        const float* __restrict__ x, const int* __restrict__ bstart,
        const uint32* __restrict__ eb,
        const uint32* __restrict__ WTmb, const float* __restrict__ bm,
        const uint32* __restrict__ WTub, const float* __restrict__ bu,
        float* __restrict__ out, int N_) {
    __shared__ float a_lds[RPB][D];          // 4 KB aggregated sums
    __shared__ float o_lds[RPB][D];          // 4 KB intermediate
    __shared__ float p_lds[4][RPB][D];       // 16 KB matvec partials (aliased)
    __shared__ int hist8[RPB], cur8[RPB], rst[RPB], dcnt[RPB];

    uint32* ebl = (uint32*)p_lds;            // [CAP]  4 KB  (sort phase only)
    uint16* stg = (uint16*)(ebl + CAP);      // [CAP]  2 KB  (sort+gather phase)

    const int tid  = threadIdx.x;
    const int lane = tid & 63;
    const int wv   = tid >> 6;

    for (int i = tid; i < RPB * D; i += 256) ((float*)a_lds)[i] = 0.f;
    if (tid < RPB) { hist8[tid] = 0; cur8[tid] = 0; }
    __syncthreads();

    const int s    = bstart[blockIdx.x];
    const int cnt  = bstart[blockIdx.x + 1] - s;
    const int cntc = min(cnt, CAP);
    const float2* __restrict__ x2 = (const float2*)x;

    // pass A: cache edges in LDS + row histogram
    for (int i = tid; i < cntc; i += 256) {
        uint32 v = eb[s + i];
        ebl[i] = v;
        atomicAdd(&hist8[(v >> 16) & 7], 1);
    }
    __syncthreads();
    if (tid == 0) {
        int run = 0;
        #pragma unroll
        for (int r = 0; r < RPB; ++r) { rst[r] = run; run += hist8[r]; dcnt[r] = hist8[r]; }
    }
    __syncthreads();

    // pass B: scatter cols into row-sorted staging (from LDS)
    for (int i = tid; i < cntc; i += 256) {
        uint32 v = ebl[i];
        int r = (v >> 16) & 7;
        int p = rst[r] + atomicAdd(&cur8[r], 1);
        stg[p] = (uint16)(v & 0xffffu);
    }
    // overflow path (cnt > CAP: ~22 sigma, never taken; correct + slow)
    for (int ii = cntc + wv * 64; ii < cnt; ii += 256) {
        int m = min(64, cnt - ii);
        uint32 v_l = (lane < m) ? eb[s + ii + lane] : 0;
        if (lane < m) atomicAdd(&dcnt[(v_l >> 16) & 7], 1);
        for (int t = 0; t < m; ++t) {
            uint32 ev = __builtin_amdgcn_readlane(v_l, t);
            float2 v = x2[((ev & 0xffffu) << 6) + lane];
            int r = (ev >> 16) & 7;
            atomicAdd(&a_lds[r][2 * lane],     v.x);
            atomicAdd(&a_lds[r][2 * lane + 1], v.y);
        }
    }
    __syncthreads();

    // ---- register gather (f32 x, features 2*lane, 2*lane+1): wave owns 2 rows
    #pragma unroll
    for (int j = 0; j < 2; ++j) {
        int r = wv * 2 + j;
        int lo = rst[r];
        int hi = lo + hist8[r];
        float ax = 0.f, ay = 0.f, bx = 0.f, by = 0.f;
        for (int ii = lo; ii < hi; ii += 64) {
            int m = min(64, hi - ii);
            int c_l = (lane < m) ? (int)stg[ii + lane] : 0;
            int t = 0;
            for (; t + 8 <= m; t += 8) {
                int c0 = __builtin_amdgcn_readlane(c_l, t + 0);
                int c1 = __builtin_amdgcn_readlane(c_l, t + 1);
                int c2 = __builtin_amdgcn_readlane(c_l, t + 2);
                int c3 = __builtin_amdgcn_readlane(c_l, t + 3);
                int c4 = __builtin_amdgcn_readlane(c_l, t + 4);
                int c5 = __builtin_amdgcn_readlane(c_l, t + 5);
                int c6 = __builtin_amdgcn_readlane(c_l, t + 6);
                int c7 = __builtin_amdgcn_readlane(c_l, t + 7);
                float2 v0 = x2[(c0 << 6) + lane];
                float2 v1 = x2[(c1 << 6) + lane];
                float2 v2 = x2[(c2 << 6) + lane];
                float2 v3 = x2[(c3 << 6) + lane];
                float2 v4 = x2[(c4 << 6) + lane];
                float2 v5 = x2[(c5 << 6) + lane];
                float2 v6 = x2[(c6 << 6) + lane];
                float2 v7 = x2[(c7 << 6) + lane];
                ax += v0.x; ay += v0.y;
                bx += v1.x; by += v1.y;
                ax += v2.x; ay += v2.y;
                bx += v3.x; by += v3.y;
                ax += v4.x; ay += v4.y;
                bx += v5.x; by += v5.y;
                ax += v6.x; ay += v6.y;
                bx += v7.x; by += v7.y;
            }
            for (; t < m; ++t) {
                int c = __builtin_amdgcn_readlane(c_l, t);
                float2 v = x2[(c << 6) + lane];
                ax += v.x; ay += v.y;
            }
        }
        a_lds[r][2 * lane]     += ax + bx;   // exclusive row per wave
        a_lds[r][2 * lane + 1] += ay + by;
    }
    __syncthreads();

    // ---- matvec 1 (k-split): wave wv covers k in [32*wv, 32*wv+32), all rows
    const int f0 = lane, f1 = lane + 64;
    const int k0b = wv * 32;

    float acc0[RPB], acc1[RPB];
    #pragma unroll
    for (int r = 0; r < RPB; ++r) { acc0[r] = 0.f; acc1[r] = 0.f; }

    #pragma unroll
    for (int kk = 0; kk < 32; kk += 4) {
        int k2 = (k0b + kk) >> 1;
        uint32 wm00 = WTmb[k2 * D + f0];
        uint32 wm01 = WTmb[(k2 + 1) * D + f0];
        uint32 wm10 = WTmb[k2 * D + f1];
        uint32 wm11 = WTmb[(k2 + 1) * D + f1];
        float w00l = bfl(wm00), w00h = bfh(wm00), w01l = bfl(wm01), w01h = bfh(wm01);
        float w10l = bfl(wm10), w10h = bfh(wm10), w11l = bfl(wm11), w11h = bfh(wm11);
        #pragma unroll
        for (int r = 0; r < RPB; ++r) {
            float4 a4 = *(const float4*)&a_lds[r][k0b + kk];
            acc0[r] += a4.x * w00l + a4.y * w00h + a4.z * w01l + a4.w * w01h;
            acc1[r] += a4.x * w10l + a4.y * w10h + a4.z * w11l + a4.w * w11h;
        }
    }
    #pragma unroll
    for (int r = 0; r < RPB; ++r) {
        p_lds[wv][r][f0] = acc0[r];
        p_lds[wv][r][f1] = acc1[r];
    }
    __syncthreads();

    // ---- reduce 1 + bias + mean: thread -> (row, 4 features) ----
    {
        int r  = tid >> 5;
        int fq = (tid & 31) * 4;
        float4 s0 = *(const float4*)&p_lds[0][r][fq];
        float4 s1 = *(const float4*)&p_lds[1][r][fq];
        float4 s2 = *(const float4*)&p_lds[2][r][fq];
        float4 s3 = *(const float4*)&p_lds[3][r][fq];
        float cntf = (float)dcnt[r];
        float inv = 1.0f / (cntf + EPS);
        float4 b4 = *(const float4*)&bm[fq];
        float4 o;
        o.x = (s0.x + s1.x + s2.x + s3.x + cntf * b4.x) * inv;
        o.y = (s0.y + s1.y + s2.y + s3.y + cntf * b4.y) * inv;
        o.z = (s0.z + s1.z + s2.z + s3.z + cntf * b4.z) * inv;
        o.w = (s0.w + s1.w + s2.w + s3.w + cntf * b4.w) * inv;
        *(float4*)&o_lds[r][fq] = o;
    }
    __syncthreads();

    // ---- matvec 2 (k-split) ----
    #pragma unroll
    for (int r = 0; r < RPB; ++r) { acc0[r] = 0.f; acc1[r] = 0.f; }

    #pragma unroll
    for (int kk = 0; kk < 32; kk += 4) {
        int k2 = (k0b + kk) >> 1;
        uint32 wu00 = WTub[k2 * D + f0];
        uint32 wu01 = WTub[(k2 + 1) * D + f0];
        uint32 wu10 = WTub[k2 * D + f1];
        uint32 wu11 = WTub[(k2 + 1) * D + f1];
        float w00l = bfl(wu00), w00h = bfh(wu00), w01l = bfl(wu01), w01h = bfh(wu01);
        float w10l = bfl(wu10), w10h = bfh(wu10), w11l = bfl(wu11), w11h = bfh(wu11);
        #pragma unroll
        for (int r = 0; r < RPB; ++r) {
            float4 a4 = *(const float4*)&o_lds[r][k0b + kk];
            acc0[r] += a4.x * w00l + a4.y * w00h + a4.z * w01l + a4.w * w01h;
            acc1[r] += a4.x * w10l + a4.y * w10h + a4.z * w11l + a4.w * w11h;
        }
    }
    __syncthreads();   // reduce-1 reads of p_lds complete before rewrite
    #pragma unroll
    for (int r = 0; r < RPB; ++r) {
        p_lds[wv][r][f0] = acc0[r];
        p_lds[wv][r][f1] = acc1[r];
    }
    __syncthreads();

    // ---- reduce 2 + bias + row-norm + store ----
    {
        int r  = tid >> 5;
        int fq = (tid & 31) * 4;
        float4 s0 = *(const float4*)&p_lds[0][r][fq];
        float4 s1 = *(const float4*)&p_lds[1][r][fq];
        float4 s2 = *(const float4*)&p_lds[2][r][fq];
        float4 s3 = *(const float4*)&p_lds[3][r][fq];
        float4 b4 = *(const float4*)&bu[fq];
        float4 t;
        t.x = s0.x + s1.x + s2.x + s3.x + b4.x;
        t.y = s0.y + s1.y + s2.y + s3.y + b4.y;
        t.z = s0.z + s1.z + s2.z + s3.z + b4.z;
        t.w = s0.w + s1.w + s2.w + s3.w + b4.w;
        float ss = t.x * t.x + t.y * t.y + t.z * t.z + t.w * t.w;
        #pragma unroll
        for (int o = 16; o > 0; o >>= 1) ss += __shfl_xor(ss, o);
        float scale = 1.0f / (sqrtf(ss) + EPS);
        int n = blockIdx.x * RPB + r;
        if (n < N_) {
            float4 w;
            w.x = t.x * scale; w.y = t.y * scale; w.z = t.z * scale; w.w = t.w * scale;
            ((float4*)out)[n * 32 + (tid & 31)] = w;
        }
    }
}

// ---------------- launch ----------------

extern "C" void kernel_launch(void* const* d_in, const int* in_sizes, int n_in,
                              void* d_out, int out_size, void* d_ws, size_t ws_size,
                              hipStream_t stream) {
    const float* x  = (const float*)d_in[0];
    const int*   ei = (const int*)d_in[1];
    const float* Wm = (const float*)d_in[2];
    const float* bm = (const float*)d_in[3];
    const float* Wu = (const float*)d_in[4];
    const float* bu = (const float*)d_in[5];
    float* out = (float*)d_out;

    const int N_ = in_sizes[0] / D;        // 10000
    const int E_ = in_sizes[1] / 2;        // 640000
    const int NB = (N_ + RPB - 1) / RPB;   // 1250 buckets

    int* bhist   = (int*)d_ws;                    // NB
    int* bcur    = bhist + NB;                    // NB
    int* bstart  = bcur + NB;                     // NB+1
    uint32* eb   = (uint32*)(bstart + NB + 1);    // E packed edges
    uint32* WTmb = eb + E_;                       // 64*128
    uint32* WTub = WTmb + 64 * D;                 // 64*128

    hipMemsetAsync(bhist, 0, 2 * (size_t)NB * sizeof(int), stream);

    int nchunk = (E_ + EPB - 1) / EPB;     // 313
    int pgrid = max(nchunk, (64 * D + 255) / 256);
    k_prep_all<<<pgrid, 256, 0, stream>>>(ei, Wm, Wu, WTmb, WTub, bhist, E_, NB);
    k_scan<<<1, 1024, 0, stream>>>(bhist, bstart, NB);
    k_bplace<<<nchunk, 256, 0, stream>>>(ei, bstart, bcur, eb, E_, NB);

    k_fused<<<NB, 256, 0, stream>>>(x, bstart, eb, WTmb, bm, WTub, bu, out, N_);
}

// Round 11
// 67.940 us; speedup vs baseline: 1.2592x; 1.2592x over previous
//
#include <hip/hip_runtime.h>
#include <hip/hip_bf16.h>

#define D 128            // D_IN == D_OUT == 128
#define RPB 8            // rows per bucket
#define NBMAX 1280       // max buckets (N<=10240)
#define EPB 8192         // edges per block in hist/place
#define CAP 1024         // staged edges per bucket (mean 512, ~22 sigma)
#define EPS 1e-8f

typedef unsigned int uint32;
typedef unsigned short uint16;

__device__ __forceinline__ uint32 f2bf_rne(float f) {
    uint32 u = __float_as_uint(f);
    return (u + 0x7fffu + ((u >> 16) & 1u)) >> 16;   // round-nearest-even
}
__device__ __forceinline__ float bfl(uint32 u) { return __uint_as_float(u << 16); }
__device__ __forceinline__ float bfh(uint32 u) { return __uint_as_float(u & 0xffff0000u); }

// -------- fused prep: xb pack + W pack + bucket histogram (first 79 blocks) ----
// xb[c*64 + j] packs features (j, j+64) of node c

__global__ __launch_bounds__(256) void k_prep_all(
        const float* __restrict__ x, const int* __restrict__ ei,
        const float* __restrict__ Wm, const float* __restrict__ Wu,
        uint32* __restrict__ xb, uint32* __restrict__ WTmb, uint32* __restrict__ WTub,
        int* __restrict__ bhist, int E_, int NX, int NB) {
    __shared__ int h[NBMAX];
    const int i = blockIdx.x * 256 + threadIdx.x;

    if (i < NX) {
        int c = i >> 6, j = i & 63;
        float lo = x[c * D + j];
        float hi = x[c * D + j + 64];
        xb[i] = f2bf_rne(lo) | (f2bf_rne(hi) << 16);
    }
    if (i < 64 * D) {
        int k2 = i >> 7, f = i & 127;
        WTmb[i] = f2bf_rne(Wm[f * D + 2 * k2]) | (f2bf_rne(Wm[f * D + 2 * k2 + 1]) << 16);
        WTub[i] = f2bf_rne(Wu[f * D + 2 * k2]) | (f2bf_rne(Wu[f * D + 2 * k2 + 1]) << 16);
    }

    int base = blockIdx.x * EPB;
    if (base < E_) {
        for (int b = threadIdx.x; b < NB; b += 256) h[b] = 0;
        __syncthreads();
        int hi2 = min(base + EPB, E_);
        for (int e = base + threadIdx.x; e < hi2; e += 256)
            atomicAdd(&h[ei[e] >> 3], 1);
        __syncthreads();
        for (int b = threadIdx.x; b < NB; b += 256)
            if (h[b]) atomicAdd(&bhist[b], h[b]);
    }
}

// ---------------- scan ----------------

__global__ void k_scan(const int* __restrict__ deg, int* __restrict__ starts, int N_) {
    __shared__ int part[1024];
    int t = threadIdx.x;
    int chunk = (N_ + 1023) / 1024;
    int s = t * chunk;
    int e = min(N_, s + chunk);
    int sum = 0;
    for (int i = s; i < e; ++i) sum += deg[i];
    part[t] = sum;
    __syncthreads();
    for (int off = 1; off < 1024; off <<= 1) {
        int u = (t >= off) ? part[t - off] : 0;
        __syncthreads();
        part[t] += u;
        __syncthreads();
    }
    int run = part[t] - sum;
    for (int i = s; i < e; ++i) { starts[i] = run; run += deg[i]; }
    if (t == 1023) starts[N_] = part[1023];
}

// ---------------- place: block-local counting sort by bucket ----------------

__global__ __launch_bounds__(512) void k_bplace(
        const int* __restrict__ ei, const int* __restrict__ bstart,
        int* __restrict__ bcur, uint32* __restrict__ eb, int E_, int NB) {
    __shared__ int h[NBMAX];
    __shared__ int off[NBMAX];
    __shared__ int bias[NBMAX];
    __shared__ uint32 stg[EPB];

    const int tid = threadIdx.x;
    const int base = blockIdx.x * EPB;
    const int nE = min(EPB, E_ - base);

    for (int i = tid; i < NB; i += 512) h[i] = 0;
    __syncthreads();

    for (int i = tid; i < nE; i += 512)
        atomicAdd(&h[ei[base + i] >> 3], 1);
    __syncthreads();

    if (tid < 64) {
        int b0 = tid * 20;
        int loc[20];
        int lsum = 0;
        #pragma unroll
        for (int j = 0; j < 20; ++j) {
            int b = b0 + j;
            int v = (b < NB) ? h[b] : 0;
            loc[j] = lsum;
            lsum += v;
        }
        int run = lsum;
        #pragma unroll
        for (int o = 1; o < 64; o <<= 1) {
            int u = __shfl_up(run, o);
            if (tid >= o) run += u;
        }
        int excl = run - lsum;
        #pragma unroll
        for (int j = 0; j < 20; ++j) {
            int b = b0 + j;
            if (b < NB) off[b] = excl + loc[j];
        }
    }
    __syncthreads();

    for (int b = tid; b < NB; b += 512) {
        int c = h[b];
        if (c) {
            int g = atomicAdd(&bcur[b], c);
            bias[b] = (bstart[b] + g) - off[b];
        }
    }
    __syncthreads();

    for (int i = tid; i < nE; i += 512) {
        int r = ei[base + i];
        int c = ei[E_ + base + i];
        int b = r >> 3;
        int p = atomicAdd(&off[b], 1);
        stg[p] = ((uint32)r << 16) | (uint32)c;
    }
    __syncthreads();

    for (int i = tid; i < nE; i += 512) {
        uint32 v = stg[i];
        int b = v >> 19;                  // row = v>>16, bucket = row>>3
        eb[bias[b] + i] = v;
    }
}

// ---------------- fused: row sort + bf16 pair-gather + k-split matvecs --------
// one block per bucket (8 rows); 256 threads = 4 waves.
// gather: wave owns 2 rows, processes 2 edges per wave-load (half-wave each).
// matvec: wave owns a 32-wide k-slice of ALL rows; partials reduced via LDS.

__global__ __launch_bounds__(256) void k_fused(
        const uint32* __restrict__ xb, const int* __restrict__ bstart,
        const uint32* __restrict__ eb,
        const uint32* __restrict__ WTmb, const float* __restrict__ bm,
        const uint32* __restrict__ WTub, const float* __restrict__ bu,
        float* __restrict__ out, int N_) {
    __shared__ float a_lds[RPB][D];          // 4 KB aggregated sums
    __shared__ float o_lds[RPB][D];          // 4 KB intermediate
    __shared__ float p_lds[4][RPB][D];       // 16 KB matvec partials (aliased)
    __shared__ int hist8[RPB], cur8[RPB], rst[RPB], dcnt[RPB];

    uint32* ebl = (uint32*)p_lds;            // [CAP]  4 KB  (sort phase only)
    uint16* stg = (uint16*)(ebl + CAP);      // [CAP]  2 KB  (sort+gather phase)

    const int tid  = threadIdx.x;
    const int lane = tid & 63;
    const int wv   = tid >> 6;

    for (int i = tid; i < RPB * D; i += 256) ((float*)a_lds)[i] = 0.f;
    if (tid < RPB) { hist8[tid] = 0; cur8[tid] = 0; }
    __syncthreads();

    const int s    = bstart[blockIdx.x];
    const int cnt  = bstart[blockIdx.x + 1] - s;
    const int cntc = min(cnt, CAP);
    const uint2* __restrict__ xb2 = (const uint2*)xb;   // row = 32 uint2

    // pass A: cache edges in LDS + row histogram
    for (int i = tid; i < cntc; i += 256) {
        uint32 v = eb[s + i];
        ebl[i] = v;
        atomicAdd(&hist8[(v >> 16) & 7], 1);
    }
    __syncthreads();
    if (tid == 0) {
        int run = 0;
        #pragma unroll
        for (int r = 0; r < RPB; ++r) { rst[r] = run; run += hist8[r]; dcnt[r] = hist8[r]; }
    }
    __syncthreads();

    // pass B: scatter cols into row-sorted staging (from LDS)
    for (int i = tid; i < cntc; i += 256) {
        uint32 v = ebl[i];
        int r = (v >> 16) & 7;
        int p = rst[r] + atomicAdd(&cur8[r], 1);
        stg[p] = (uint16)(v & 0xffffu);
    }
    // overflow path (cnt > CAP: ~22 sigma, never taken; correct + slow)
    for (int ii = cntc + wv * 64; ii < cnt; ii += 256) {
        int m = min(64, cnt - ii);
        uint32 v_l = (lane < m) ? eb[s + ii + lane] : 0;
        if (lane < m) atomicAdd(&dcnt[(v_l >> 16) & 7], 1);
        for (int t = 0; t < m; ++t) {
            uint32 ev = __builtin_amdgcn_readlane(v_l, t);
            uint32 v = xb[((ev & 0xffffu) << 6) + lane];
            int r = (ev >> 16) & 7;
            atomicAdd(&a_lds[r][lane],      bfl(v));
            atomicAdd(&a_lds[r][lane + 64], bfh(v));
        }
    }
    __syncthreads();

    // ---- pair-gather: wave owns rows {2wv, 2wv+1}; 2 edges per wave-load ----
    // lane = 32*half + lf;  lane loads xb2[c*32 + lf] = features (2lf, 2lf+64,
    // 2lf+1, 2lf+65) of its half's edge.
    const int half = lane >> 5;
    const int lf   = lane & 31;

    #pragma unroll
    for (int j = 0; j < 2; ++j) {
        int r  = wv * 2 + j;
        int lo = rst[r];
        int n  = hist8[r];
        int np = n >> 1;

        float2 aA = make_float2(0.f, 0.f);   // features (2lf, 2lf+1)
        float2 aB = make_float2(0.f, 0.f);   // features (2lf+64, 2lf+65)

        int it = 0;
        for (; it + 4 <= np; it += 4) {
            int c0 = stg[lo + 2 * (it + 0) + half];
            int c1 = stg[lo + 2 * (it + 1) + half];
            int c2 = stg[lo + 2 * (it + 2) + half];
            int c3 = stg[lo + 2 * (it + 3) + half];
            uint2 v0 = xb2[(c0 << 5) + lf];
            uint2 v1 = xb2[(c1 << 5) + lf];
            uint2 v2 = xb2[(c2 << 5) + lf];
            uint2 v3 = xb2[(c3 << 5) + lf];
            aA.x += bfl(v0.x); aA.y += bfl(v0.y);
            aB.x += bfh(v0.x); aB.y += bfh(v0.y);
            aA.x += bfl(v1.x); aA.y += bfl(v1.y);
            aB.x += bfh(v1.x); aB.y += bfh(v1.y);
            aA.x += bfl(v2.x); aA.y += bfl(v2.y);
            aB.x += bfh(v2.x); aB.y += bfh(v2.y);
            aA.x += bfl(v3.x); aA.y += bfl(v3.y);
            aB.x += bfh(v3.x); aB.y += bfh(v3.y);
        }
        for (; it < np; ++it) {
            int c = stg[lo + 2 * it + half];
            uint2 v = xb2[(c << 5) + lf];
            aA.x += bfl(v.x); aA.y += bfl(v.y);
            aB.x += bfh(v.x); aB.y += bfh(v.y);
        }
        // combine halves
        aA.x += __shfl_xor(aA.x, 32); aA.y += __shfl_xor(aA.y, 32);
        aB.x += __shfl_xor(aB.x, 32); aB.y += __shfl_xor(aB.y, 32);
        if (half == 0) {
            if (n & 1) {   // odd tail edge, lanes 0-31 only
                int c = stg[lo + n - 1];
                uint2 v = xb2[(c << 5) + lf];
                aA.x += bfl(v.x); aA.y += bfl(v.y);
                aB.x += bfh(v.x); aB.y += bfh(v.y);
            }
            float2 old0 = *(float2*)&a_lds[r][2 * lf];
            float2 old1 = *(float2*)&a_lds[r][2 * lf + 64];
            old0.x += aA.x; old0.y += aA.y;
            old1.x += aB.x; old1.y += aB.y;
            *(float2*)&a_lds[r][2 * lf]      = old0;
            *(float2*)&a_lds[r][2 * lf + 64] = old1;
        }
    }
    __syncthreads();

    // ---- matvec 1 (k-split): wave wv covers k in [32*wv, 32*wv+32), all rows
    const int f0 = lane, f1 = lane + 64;
    const int k0b = wv * 32;

    float acc0[RPB], acc1[RPB];
    #pragma unroll
    for (int r = 0; r < RPB; ++r) { acc0[r] = 0.f; acc1[r] = 0.f; }

    #pragma unroll
    for (int kk = 0; kk < 32; kk += 4) {
        int k2 = (k0b + kk) >> 1;
        uint32 wm00 = WTmb[k2 * D + f0];
        uint32 wm01 = WTmb[(k2 + 1) * D + f0];
        uint32 wm10 = WTmb[k2 * D + f1];
        uint32 wm11 = WTmb[(k2 + 1) * D + f1];
        float w00l = bfl(wm00), w00h = bfh(wm00), w01l = bfl(wm01), w01h = bfh(wm01);
        float w10l = bfl(wm10), w10h = bfh(wm10), w11l = bfl(wm11), w11h = bfh(wm11);
        #pragma unroll
        for (int r = 0; r < RPB; ++r) {
            float4 a4 = *(const float4*)&a_lds[r][k0b + kk];
            acc0[r] += a4.x * w00l + a4.y * w00h + a4.z * w01l + a4.w * w01h;
            acc1[r] += a4.x * w10l + a4.y * w10h + a4.z * w11l + a4.w * w11h;
        }
    }
    #pragma unroll
    for (int r = 0; r < RPB; ++r) {
        p_lds[wv][r][f0] = acc0[r];
        p_lds[wv][r][f1] = acc1[r];
    }
    __syncthreads();

    // ---- reduce 1 + bias + mean: thread -> (row, 4 features) ----
    {
        int r  = tid >> 5;
        int fq = (tid & 31) * 4;
        float4 s0 = *(const float4*)&p_lds[0][r][fq];
        float4 s1 = *(const float4*)&p_lds[1][r][fq];
        float4 s2 = *(const float4*)&p_lds[2][r][fq];
        float4 s3 = *(const float4*)&p_lds[3][r][fq];
        float cntf = (float)dcnt[r];
        float inv = 1.0f / (cntf + EPS);
        float4 b4 = *(const float4*)&bm[fq];
        float4 o;
        o.x = (s0.x + s1.x + s2.x + s3.x + cntf * b4.x) * inv;
        o.y = (s0.y + s1.y + s2.y + s3.y + cntf * b4.y) * inv;
        o.z = (s0.z + s1.z + s2.z + s3.z + cntf * b4.z) * inv;
        o.w = (s0.w + s1.w + s2.w + s3.w + cntf * b4.w) * inv;
        *(float4*)&o_lds[r][fq] = o;
    }
    __syncthreads();

    // ---- matvec 2 (k-split) ----
    #pragma unroll
    for (int r = 0; r < RPB; ++r) { acc0[r] = 0.f; acc1[r] = 0.f; }

    #pragma unroll
    for (int kk = 0; kk < 32; kk += 4) {
        int k2 = (k0b + kk) >> 1;
        uint32 wu00 = WTub[k2 * D + f0];
        uint32 wu01 = WTub[(k2 + 1) * D + f0];
        uint32 wu10 = WTub[k2 * D + f1];
        uint32 wu11 = WTub[(k2 + 1) * D + f1];
        float w00l = bfl(wu00), w00h = bfh(wu00), w01l = bfl(wu01), w01h = bfh(wu01);
        float w10l = bfl(wu10), w10h = bfh(wu10), w11l = bfl(wu11), w11h = bfh(wu11);
        #pragma unroll
        for (int r = 0; r < RPB; ++r) {
            float4 a4 = *(const float4*)&o_lds[r][k0b + kk];
            acc0[r] += a4.x * w00l + a4.y * w00h + a4.z * w01l + a4.w * w01h;
            acc1[r] += a4.x * w10l + a4.y * w10h + a4.z * w11l + a4.w * w11h;
        }
    }
    __syncthreads();   // reduce-1 reads of p_lds complete before rewrite
    #pragma unroll
    for (int r = 0; r < RPB; ++r) {
        p_lds[wv][r][f0] = acc0[r];
        p_lds[wv][r][f1] = acc1[r];
    }
    __syncthreads();

    // ---- reduce 2 + bias + row-norm + store ----
    {
        int r  = tid >> 5;
        int fq = (tid & 31) * 4;
        float4 s0 = *(const float4*)&p_lds[0][r][fq];
        float4 s1 = *(const float4*)&p_lds[1][r][fq];
        float4 s2 = *(const float4*)&p_lds[2][r][fq];
        float4 s3 = *(const float4*)&p_lds[3][r][fq];
        float4 b4 = *(const float4*)&bu[fq];
        float4 t;
        t.x = s0.x + s1.x + s2.x + s3.x + b4.x;
        t.y = s0.y + s1.y + s2.y + s3.y + b4.y;
        t.z = s0.z + s1.z + s2.z + s3.z + b4.z;
        t.w = s0.w + s1.w + s2.w + s3.w + b4.w;
        float ss = t.x * t.x + t.y * t.y + t.z * t.z + t.w * t.w;
        #pragma unroll
        for (int o = 16; o > 0; o >>= 1) ss += __shfl_xor(ss, o);
        float scale = 1.0f / (sqrtf(ss) + EPS);
        int n = blockIdx.x * RPB + r;
        if (n < N_) {
            float4 w;
            w.x = t.x * scale; w.y = t.y * scale; w.z = t.z * scale; w.w = t.w * scale;
            ((float4*)out)[n * 32 + (tid & 31)] = w;
        }
    }
}

// ---------------- launch ----------------

extern "C" void kernel_launch(void* const* d_in, const int* in_sizes, int n_in,
                              void* d_out, int out_size, void* d_ws, size_t ws_size,
                              hipStream_t stream) {
    const float* x  = (const float*)d_in[0];
    const int*   ei = (const int*)d_in[1];
    const float* Wm = (const float*)d_in[2];
    const float* bm = (const float*)d_in[3];
    const float* Wu = (const float*)d_in[4];
    const float* bu = (const float*)d_in[5];
    float* out = (float*)d_out;

    const int N_ = in_sizes[0] / D;        // 10000
    const int E_ = in_sizes[1] / 2;        // 640000
    const int NX = N_ * (D / 2);           // packed x pairs
    const int NB = (N_ + RPB - 1) / RPB;   // 1250 buckets

    int* bhist   = (int*)d_ws;                    // NB
    int* bcur    = bhist + NB;                    // NB
    int* bstart  = bcur + NB;                     // NB+1
    uint32* xb   = (uint32*)(bstart + NB + 1);    // N*64
    uint32* eb   = xb + NX;                       // E packed edges
    uint32* WTmb = eb + E_;                       // 64*128
    uint32* WTub = WTmb + 64 * D;                 // 64*128

    hipMemsetAsync(bhist, 0, 2 * (size_t)NB * sizeof(int), stream);

    int pgrid = (max(NX, E_) + 255) / 256;   // 2500 (hist in first 79 blocks)
    k_prep_all<<<pgrid, 256, 0, stream>>>(x, ei, Wm, Wu, xb, WTmb, WTub, bhist, E_, NX, NB);
    k_scan<<<1, 1024, 0, stream>>>(bhist, bstart, NB);

    int nchunk = (E_ + EPB - 1) / EPB;     // 79
    k_bplace<<<nchunk, 512, 0, stream>>>(ei, bstart, bcur, eb, E_, NB);

    k_fused<<<NB, 256, 0, stream>>>(xb, bstart, eb, WTmb, bm, WTub, bu, out, N_);
}

// Round 12
// 53.427 us; speedup vs baseline: 1.6012x; 1.2716x over previous
//
#include <hip/hip_runtime.h>
#include <hip/hip_bf16.h>

#define D 128            // D_IN == D_OUT == 128
#define RPB 8            // rows per bucket
#define NBMAX 1280       // max buckets (N<=10240)
#define EPB 8192         // edges per chunk in stage sort
#define CAP 1024         // fixed eb stride per bucket (mean 512, +22 sigma)
#define OVFCAP 65536     // overflow list capacity (never used in practice)
#define EPS 1e-8f

typedef unsigned int uint32;
typedef unsigned short uint16;

__device__ __forceinline__ uint32 f2bf_rne(float f) {
    uint32 u = __float_as_uint(f);
    return (u + 0x7fffu + ((u >> 16) & 1u)) >> 16;   // round-nearest-even
}
__device__ __forceinline__ float bfl(uint32 u) { return __uint_as_float(u << 16); }
__device__ __forceinline__ float bfh(uint32 u) { return __uint_as_float(u & 0xffff0000u); }

// ---------------- stage: role-split blocks ----------------
// blocks [0, nchunk): counting-sort an EPB edge chunk into fixed-stride eb
// blocks [nchunk, ..): pack xb (and WT in the first 16 of them)
// xb[c*64 + j] packs features (j, j+64) of node c

__global__ __launch_bounds__(512) void k_stage(
        const float* __restrict__ x, const int* __restrict__ ei,
        const float* __restrict__ Wm, const float* __restrict__ Wu,
        uint32* __restrict__ xb, uint32* __restrict__ WTmb, uint32* __restrict__ WTub,
        int* __restrict__ bcur, int* __restrict__ ovfn, uint32* __restrict__ ovf,
        uint32* __restrict__ eb, int E_, int NX, int NB, int nchunk) {
    const int tid = threadIdx.x;

    if (blockIdx.x >= nchunk) {
        // ---- pack role ----
        int i = (blockIdx.x - nchunk) * 512 + tid;
        if (i < NX) {
            int c = i >> 6, j = i & 63;
            float lo = x[c * D + j];
            float hi = x[c * D + j + 64];
            xb[i] = f2bf_rne(lo) | (f2bf_rne(hi) << 16);
        }
        if (i < 64 * D) {
            int k2 = i >> 7, f = i & 127;
            WTmb[i] = f2bf_rne(Wm[f * D + 2 * k2]) | (f2bf_rne(Wm[f * D + 2 * k2 + 1]) << 16);
            WTub[i] = f2bf_rne(Wu[f * D + 2 * k2]) | (f2bf_rne(Wu[f * D + 2 * k2 + 1]) << 16);
        }
        return;
    }

    // ---- sort role ----
    __shared__ int h[NBMAX];
    __shared__ int off[NBMAX];
    __shared__ int bias[NBMAX];
    __shared__ uint32 stg[EPB];

    const int base = blockIdx.x * EPB;
    const int nE = min(EPB, E_ - base);

    for (int i = tid; i < NB; i += 512) h[i] = 0;
    __syncthreads();

    for (int i = tid; i < nE; i += 512)
        atomicAdd(&h[ei[base + i] >> 3], 1);
    __syncthreads();

    if (tid < 64) {   // exclusive scan of h by one wave (20 bins per lane)
        int b0 = tid * 20;
        int loc[20];
        int lsum = 0;
        #pragma unroll
        for (int j = 0; j < 20; ++j) {
            int b = b0 + j;
            int v = (b < NB) ? h[b] : 0;
            loc[j] = lsum;
            lsum += v;
        }
        int run = lsum;
        #pragma unroll
        for (int o = 1; o < 64; o <<= 1) {
            int u = __shfl_up(run, o);
            if (tid >= o) run += u;
        }
        int excl = run - lsum;
        #pragma unroll
        for (int j = 0; j < 20; ++j) {
            int b = b0 + j;
            if (b < NB) off[b] = excl + loc[j];
        }
    }
    __syncthreads();

    // reserve global ranges per bucket (fixed stride: bucket b starts at b*CAP)
    for (int b = tid; b < NB; b += 512) {
        int c = h[b];
        if (c) {
            int g = atomicAdd(&bcur[b], c);
            bias[b] = (b << 10) + g - off[b];
        }
    }
    __syncthreads();

    // scatter into bucket-sorted staging
    for (int i = tid; i < nE; i += 512) {
        int r = ei[base + i];
        int c = ei[E_ + base + i];
        int b = r >> 3;
        int p = atomicAdd(&off[b], 1);
        stg[p] = ((uint32)r << 16) | (uint32)c;
    }
    __syncthreads();

    // linear write-out; positions beyond CAP spill to overflow list
    for (int i = tid; i < nE; i += 512) {
        uint32 v = stg[i];
        int b = v >> 19;                  // row = v>>16, bucket = row>>3
        int p = bias[b] + i;
        if (p - (b << 10) < CAP) {
            eb[p] = v;
        } else {
            int o = atomicAdd(ovfn, 1);
            if (o < OVFCAP) ovf[o] = v;
        }
    }
}

// ---------------- fused: row sort + quad bf16 gather + k-split matvecs -------
// one block per bucket (8 rows); 256 threads = 4 waves.
// gather: wave owns 2 rows, 4 edges per wave-iteration (16 lanes x uint4 each).
// matvec: wave owns a 32-wide k-slice of ALL rows; partials reduced via LDS.

__global__ __launch_bounds__(256) void k_fused(
        const uint32* __restrict__ xb, const int* __restrict__ bcur,
        const uint32* __restrict__ eb,
        const int* __restrict__ ovfn, const uint32* __restrict__ ovf,
        const uint32* __restrict__ WTmb, const float* __restrict__ bm,
        const uint32* __restrict__ WTub, const float* __restrict__ bu,
        float* __restrict__ out, int N_) {
    __shared__ float a_lds[RPB][D];          // 4 KB aggregated sums
    __shared__ float o_lds[RPB][D];          // 4 KB intermediate
    __shared__ float p_lds[4][RPB][D];       // 16 KB matvec partials (aliased)
    __shared__ int hist8[RPB], cur8[RPB], rst[RPB], dcnt[RPB];

    uint32* ebl = (uint32*)p_lds;            // [CAP]  4 KB  (sort phase only)
    uint16* stg = (uint16*)(ebl + CAP);      // [CAP]  2 KB  (sort+gather phase)

    const int tid  = threadIdx.x;
    const int lane = tid & 63;
    const int wv   = tid >> 6;

    for (int i = tid; i < RPB * D; i += 256) ((float*)a_lds)[i] = 0.f;
    if (tid < RPB) { hist8[tid] = 0; cur8[tid] = 0; }
    __syncthreads();

    const int ebase = blockIdx.x << 10;
    const int cnt   = bcur[blockIdx.x];
    const int cntc  = min(cnt, CAP);

    // pass A: cache edges in LDS + ballot row histogram
    {
        int cnt_loc = 0;
        for (int i0 = 0; i0 < cntc; i0 += 256) {
            int i = i0 + tid;
            bool valid = i < cntc;
            uint32 v = valid ? eb[ebase + i] : 0u;
            if (valid) ebl[i] = v;
            int myr = (v >> 16) & 7;
            #pragma unroll
            for (int r = 0; r < RPB; ++r) {
                unsigned long long m = __ballot(valid && (myr == r));
                if (lane == r) cnt_loc += __popcll(m);
            }
        }
        if (lane < RPB && cnt_loc) atomicAdd(&hist8[lane], cnt_loc);
    }
    __syncthreads();
    if (tid == 0) {
        int run = 0;
        #pragma unroll
        for (int r = 0; r < RPB; ++r) { rst[r] = run; run += hist8[r]; dcnt[r] = hist8[r]; }
    }
    __syncthreads();

    // pass B: scatter cols into row-sorted staging (from LDS)
    for (int i = tid; i < cntc; i += 256) {
        uint32 v = ebl[i];
        int r = (v >> 16) & 7;
        int p = rst[r] + atomicAdd(&cur8[r], 1);
        stg[p] = (uint16)(v & 0xffffu);
    }
    // overflow path (cnt > CAP: never taken in practice; correct + slow)
    if (cnt > CAP) {
        int no = min(*ovfn, OVFCAP);
        for (int ii = wv * 64; ii < no; ii += 256) {
            int m = min(64, no - ii);
            uint32 v_l = 0;
            bool mine = false;
            if (lane < m) {
                v_l = ovf[ii + lane];
                mine = ((v_l >> 19) == (uint32)blockIdx.x);
                if (mine) atomicAdd(&dcnt[(v_l >> 16) & 7], 1);
            }
            for (int t = 0; t < m; ++t) {
                uint32 ev = __builtin_amdgcn_readlane(v_l, t);
                if ((ev >> 19) != (uint32)blockIdx.x) continue;
                uint32 v = xb[((ev & 0xffffu) << 6) + lane];
                int r = (ev >> 16) & 7;
                atomicAdd(&a_lds[r][lane],      bfl(v));
                atomicAdd(&a_lds[r][lane + 64], bfh(v));
            }
        }
    }
    __syncthreads();

    // ---- quad gather: wave owns rows {2wv, 2wv+1}; 4 edges per iteration ----
    // lane = 16*q + lf; lane loads xb4[c*16 + lf] = features
    // (4lf..4lf+3, 4lf+64..4lf+67) of its quarter's edge.
    const int q  = lane >> 4;
    const int lf = lane & 15;
    const uint4* __restrict__ xb4 = (const uint4*)xb;   // row = 16 uint4

    #pragma unroll
    for (int j = 0; j < 2; ++j) {
        int r  = wv * 2 + j;
        int lo = rst[r];
        int n  = hist8[r];
        int nq = n >> 2;

        float4 aL = make_float4(0.f, 0.f, 0.f, 0.f);
        float4 aH = make_float4(0.f, 0.f, 0.f, 0.f);

        int it = 0;
        for (; it + 2 <= nq; it += 2) {
            int cA = stg[lo + 4 * it + q];
            int cB = stg[lo + 4 * (it + 1) + q];
            uint4 vA = xb4[(cA << 4) + lf];
            uint4 vB = xb4[(cB << 4) + lf];
            aL.x += bfl(vA.x); aH.x += bfh(vA.x);
            aL.y += bfl(vA.y); aH.y += bfh(vA.y);
            aL.z += bfl(vA.z); aH.z += bfh(vA.z);
            aL.w += bfl(vA.w); aH.w += bfh(vA.w);
            aL.x += bfl(vB.x); aH.x += bfh(vB.x);
            aL.y += bfl(vB.y); aH.y += bfh(vB.y);
            aL.z += bfl(vB.z); aH.z += bfh(vB.z);
            aL.w += bfl(vB.w); aH.w += bfh(vB.w);
        }
        for (; it < nq; ++it) {
            int c = stg[lo + 4 * it + q];
            uint4 v = xb4[(c << 4) + lf];
            aL.x += bfl(v.x); aH.x += bfh(v.x);
            aL.y += bfl(v.y); aH.y += bfh(v.y);
            aL.z += bfl(v.z); aH.z += bfh(v.z);
            aL.w += bfl(v.w); aH.w += bfh(v.w);
        }
        int rem = n & 3;
        if (q < rem) {     // tail edges handled one per quarter
            int c = stg[lo + 4 * nq + q];
            uint4 v = xb4[(c << 4) + lf];
            aL.x += bfl(v.x); aH.x += bfh(v.x);
            aL.y += bfl(v.y); aH.y += bfh(v.y);
            aL.z += bfl(v.z); aH.z += bfh(v.z);
            aL.w += bfl(v.w); aH.w += bfh(v.w);
        }
        // combine quarters
        aL.x += __shfl_xor(aL.x, 16); aL.x += __shfl_xor(aL.x, 32);
        aL.y += __shfl_xor(aL.y, 16); aL.y += __shfl_xor(aL.y, 32);
        aL.z += __shfl_xor(aL.z, 16); aL.z += __shfl_xor(aL.z, 32);
        aL.w += __shfl_xor(aL.w, 16); aL.w += __shfl_xor(aL.w, 32);
        aH.x += __shfl_xor(aH.x, 16); aH.x += __shfl_xor(aH.x, 32);
        aH.y += __shfl_xor(aH.y, 16); aH.y += __shfl_xor(aH.y, 32);
        aH.z += __shfl_xor(aH.z, 16); aH.z += __shfl_xor(aH.z, 32);
        aH.w += __shfl_xor(aH.w, 16); aH.w += __shfl_xor(aH.w, 32);
        if (q == 0) {      // exclusive (row, lf) per lane: plain RMW
            float4 o0 = *(const float4*)&a_lds[r][4 * lf];
            float4 o1 = *(const float4*)&a_lds[r][4 * lf + 64];
            o0.x += aL.x; o0.y += aL.y; o0.z += aL.z; o0.w += aL.w;
            o1.x += aH.x; o1.y += aH.y; o1.z += aH.z; o1.w += aH.w;
            *(float4*)&a_lds[r][4 * lf]      = o0;
            *(float4*)&a_lds[r][4 * lf + 64] = o1;
        }
    }
    __syncthreads();

    // ---- matvec 1 (k-split): wave wv covers k in [32*wv, 32*wv+32), all rows
    const int f0 = lane, f1 = lane + 64;
    const int k0b = wv * 32;

    float acc0[RPB], acc1[RPB];
    #pragma unroll
    for (int r = 0; r < RPB; ++r) { acc0[r] = 0.f; acc1[r] = 0.f; }

    #pragma unroll
    for (int kk = 0; kk < 32; kk += 4) {
        int k2 = (k0b + kk) >> 1;
        uint32 wm00 = WTmb[k2 * D + f0];
        uint32 wm01 = WTmb[(k2 + 1) * D + f0];
        uint32 wm10 = WTmb[k2 * D + f1];
        uint32 wm11 = WTmb[(k2 + 1) * D + f1];
        float w00l = bfl(wm00), w00h = bfh(wm00), w01l = bfl(wm01), w01h = bfh(wm01);
        float w10l = bfl(wm10), w10h = bfh(wm10), w11l = bfl(wm11), w11h = bfh(wm11);
        #pragma unroll
        for (int r = 0; r < RPB; ++r) {
            float4 a4 = *(const float4*)&a_lds[r][k0b + kk];
            acc0[r] += a4.x * w00l + a4.y * w00h + a4.z * w01l + a4.w * w01h;
            acc1[r] += a4.x * w10l + a4.y * w10h + a4.z * w11l + a4.w * w11h;
        }
    }
    #pragma unroll
    for (int r = 0; r < RPB; ++r) {
        p_lds[wv][r][f0] = acc0[r];
        p_lds[wv][r][f1] = acc1[r];
    }
    __syncthreads();

    // ---- reduce 1 + bias + mean: thread -> (row, 4 features) ----
    {
        int r  = tid >> 5;
        int fq = (tid & 31) * 4;
        float4 s0 = *(const float4*)&p_lds[0][r][fq];
        float4 s1 = *(const float4*)&p_lds[1][r][fq];
        float4 s2 = *(const float4*)&p_lds[2][r][fq];
        float4 s3 = *(const float4*)&p_lds[3][r][fq];
        float cntf = (float)dcnt[r];
        float inv = 1.0f / (cntf + EPS);
        float4 b4 = *(const float4*)&bm[fq];
        float4 o;
        o.x = (s0.x + s1.x + s2.x + s3.x + cntf * b4.x) * inv;
        o.y = (s0.y + s1.y + s2.y + s3.y + cntf * b4.y) * inv;
        o.z = (s0.z + s1.z + s2.z + s3.z + cntf * b4.z) * inv;
        o.w = (s0.w + s1.w + s2.w + s3.w + cntf * b4.w) * inv;
        *(float4*)&o_lds[r][fq] = o;
    }
    __syncthreads();

    // ---- matvec 2 (k-split) ----
    #pragma unroll
    for (int r = 0; r < RPB; ++r) { acc0[r] = 0.f; acc1[r] = 0.f; }

    #pragma unroll
    for (int kk = 0; kk < 32; kk += 4) {
        int k2 = (k0b + kk) >> 1;
        uint32 wu00 = WTub[k2 * D + f0];
        uint32 wu01 = WTub[(k2 + 1) * D + f0];
        uint32 wu10 = WTub[k2 * D + f1];
        uint32 wu11 = WTub[(k2 + 1) * D + f1];
        float w00l = bfl(wu00), w00h = bfh(wu00), w01l = bfl(wu01), w01h = bfh(wu01);
        float w10l = bfl(wu10), w10h = bfh(wu10), w11l = bfl(wu11), w11h = bfh(wu11);
        #pragma unroll
        for (int r = 0; r < RPB; ++r) {
            float4 a4 = *(const float4*)&o_lds[r][k0b + kk];
            acc0[r] += a4.x * w00l + a4.y * w00h + a4.z * w01l + a4.w * w01h;
            acc1[r] += a4.x * w10l + a4.y * w10h + a4.z * w11l + a4.w * w11h;
        }
    }
    __syncthreads();   // reduce-1 reads of p_lds complete before rewrite
    #pragma unroll
    for (int r = 0; r < RPB; ++r) {
        p_lds[wv][r][f0] = acc0[r];
        p_lds[wv][r][f1] = acc1[r];
    }
    __syncthreads();

    // ---- reduce 2 + bias + row-norm + store ----
    {
        int r  = tid >> 5;
        int fq = (tid & 31) * 4;
        float4 s0 = *(const float4*)&p_lds[0][r][fq];
        float4 s1 = *(const float4*)&p_lds[1][r][fq];
        float4 s2 = *(const float4*)&p_lds[2][r][fq];
        float4 s3 = *(const float4*)&p_lds[3][r][fq];
        float4 b4 = *(const float4*)&bu[fq];
        float4 t;
        t.x = s0.x + s1.x + s2.x + s3.x + b4.x;
        t.y = s0.y + s1.y + s2.y + s3.y + b4.y;
        t.z = s0.z + s1.z + s2.z + s3.z + b4.z;
        t.w = s0.w + s1.w + s2.w + s3.w + b4.w;
        float ss = t.x * t.x + t.y * t.y + t.z * t.z + t.w * t.w;
        #pragma unroll
        for (int o = 16; o > 0; o >>= 1) ss += __shfl_xor(ss, o);
        float scale = 1.0f / (sqrtf(ss) + EPS);
        int n = blockIdx.x * RPB + r;
        if (n < N_) {
            float4 w;
            w.x = t.x * scale; w.y = t.y * scale; w.z = t.z * scale; w.w = t.w * scale;
            ((float4*)out)[n * 32 + (tid & 31)] = w;
        }
    }
}

// ---------------- launch ----------------

extern "C" void kernel_launch(void* const* d_in, const int* in_sizes, int n_in,
                              void* d_out, int out_size, void* d_ws, size_t ws_size,
                              hipStream_t stream) {
    const float* x  = (const float*)d_in[0];
    const int*   ei = (const int*)d_in[1];
    const float* Wm = (const float*)d_in[2];
    const float* bm = (const float*)d_in[3];
    const float* Wu = (const float*)d_in[4];
    const float* bu = (const float*)d_in[5];
    float* out = (float*)d_out;

    const int N_ = in_sizes[0] / D;        // 10000
    const int E_ = in_sizes[1] / 2;        // 640000
    const int NX = N_ * (D / 2);           // packed x pairs
    const int NB = (N_ + RPB - 1) / RPB;   // 1250 buckets

    uint32* xb   = (uint32*)d_ws;                 // NX          (16B aligned)
    uint32* eb   = xb + NX;                       // NB*CAP
    uint32* WTmb = eb + (size_t)NB * CAP;         // 64*128
    uint32* WTub = WTmb + 64 * D;                 // 64*128
    int*    bcur = (int*)(WTub + 64 * D);         // NB
    int*    ovfn = bcur + NB;                     // 1
    uint32* ovf  = (uint32*)(ovfn + 1);           // OVFCAP

    hipMemsetAsync(bcur, 0, (size_t)(NB + 1) * sizeof(int), stream);

    const int nchunk = (E_ + EPB - 1) / EPB;          // 79
    const int npack  = (NX + 511) / 512;              // 1250
    k_stage<<<nchunk + npack, 512, 0, stream>>>(
        x, ei, Wm, Wu, xb, WTmb, WTub, bcur, ovfn, ovf, eb, E_, NX, NB, nchunk);

    k_fused<<<NB, 256, 0, stream>>>(xb, bcur, eb, ovfn, ovf,
                                    WTmb, bm, WTub, bu, out, N_);
}

// Round 13
// 51.088 us; speedup vs baseline: 1.6746x; 1.0458x over previous
//
#include <hip/hip_runtime.h>
#include <hip/hip_bf16.h>

#define D 128            // D_IN == D_OUT == 128
#define RPB 8            // rows per bucket
#define NBMAX 1280       // max buckets (N<=10240)
#define EPB 8192         // edges per chunk in stage sort
#define CAP 1024         // fixed eb stride per bucket (mean 512, +22 sigma)
#define OVFCAP 65536     // overflow list capacity (never used in practice)
#define EPS 1e-8f

typedef unsigned int uint32;
typedef unsigned short uint16;

__device__ __forceinline__ uint32 f2bf_rne(float f) {
    uint32 u = __float_as_uint(f);
    return (u + 0x7fffu + ((u >> 16) & 1u)) >> 16;   // round-nearest-even
}
__device__ __forceinline__ float bfl(uint32 u) { return __uint_as_float(u << 16); }
__device__ __forceinline__ float bfh(uint32 u) { return __uint_as_float(u & 0xffff0000u); }

// ---------------- zero: replaces hipMemsetAsync (runtime fill costs ~40us) ----

__global__ __launch_bounds__(256) void k_zero(int* __restrict__ bcur, int n) {
    int i = blockIdx.x * 256 + threadIdx.x;
    if (i < n) bcur[i] = 0;      // covers bcur[NB] + ovfn (last element)
}

// ---------------- stage: role-split blocks ----------------
// blocks [0, nchunk): counting-sort an EPB edge chunk into fixed-stride eb
// blocks [nchunk, ..): pack xb (and WT in the first 16 of them)
// xb[c*64 + j] packs features (j, j+64) of node c

__global__ __launch_bounds__(512) void k_stage(
        const float* __restrict__ x, const int* __restrict__ ei,
        const float* __restrict__ Wm, const float* __restrict__ Wu,
        uint32* __restrict__ xb, uint32* __restrict__ WTmb, uint32* __restrict__ WTub,
        int* __restrict__ bcur, int* __restrict__ ovfn, uint32* __restrict__ ovf,
        uint32* __restrict__ eb, int E_, int NX, int NB, int nchunk) {
    const int tid = threadIdx.x;

    if (blockIdx.x >= nchunk) {
        // ---- pack role ----
        int i = (blockIdx.x - nchunk) * 512 + tid;
        if (i < NX) {
            int c = i >> 6, j = i & 63;
            float lo = x[c * D + j];
            float hi = x[c * D + j + 64];
            xb[i] = f2bf_rne(lo) | (f2bf_rne(hi) << 16);
        }
        if (i < 64 * D) {
            int k2 = i >> 7, f = i & 127;
            WTmb[i] = f2bf_rne(Wm[f * D + 2 * k2]) | (f2bf_rne(Wm[f * D + 2 * k2 + 1]) << 16);
            WTub[i] = f2bf_rne(Wu[f * D + 2 * k2]) | (f2bf_rne(Wu[f * D + 2 * k2 + 1]) << 16);
        }
        return;
    }

    // ---- sort role ----
    __shared__ int h[NBMAX];
    __shared__ int off[NBMAX];
    __shared__ int bias[NBMAX];
    __shared__ uint32 stg[EPB];

    const int base = blockIdx.x * EPB;
    const int nE = min(EPB, E_ - base);

    for (int i = tid; i < NB; i += 512) h[i] = 0;
    __syncthreads();

    for (int i = tid; i < nE; i += 512)
        atomicAdd(&h[ei[base + i] >> 3], 1);
    __syncthreads();

    if (tid < 64) {   // exclusive scan of h by one wave (20 bins per lane)
        int b0 = tid * 20;
        int loc[20];
        int lsum = 0;
        #pragma unroll
        for (int j = 0; j < 20; ++j) {
            int b = b0 + j;
            int v = (b < NB) ? h[b] : 0;
            loc[j] = lsum;
            lsum += v;
        }
        int run = lsum;
        #pragma unroll
        for (int o = 1; o < 64; o <<= 1) {
            int u = __shfl_up(run, o);
            if (tid >= o) run += u;
        }
        int excl = run - lsum;
        #pragma unroll
        for (int j = 0; j < 20; ++j) {
            int b = b0 + j;
            if (b < NB) off[b] = excl + loc[j];
        }
    }
    __syncthreads();

    // reserve global ranges per bucket (fixed stride: bucket b starts at b*CAP)
    for (int b = tid; b < NB; b += 512) {
        int c = h[b];
        if (c) {
            int g = atomicAdd(&bcur[b], c);
            bias[b] = (b << 10) + g - off[b];
        }
    }
    __syncthreads();

    // scatter into bucket-sorted staging
    for (int i = tid; i < nE; i += 512) {
        int r = ei[base + i];
        int c = ei[E_ + base + i];
        int b = r >> 3;
        int p = atomicAdd(&off[b], 1);
        stg[p] = ((uint32)r << 16) | (uint32)c;
    }
    __syncthreads();

    // linear write-out; positions beyond CAP spill to overflow list
    for (int i = tid; i < nE; i += 512) {
        uint32 v = stg[i];
        int b = v >> 19;                  // row = v>>16, bucket = row>>3
        int p = bias[b] + i;
        if (p - (b << 10) < CAP) {
            eb[p] = v;
        } else {
            int o = atomicAdd(ovfn, 1);
            if (o < OVFCAP) ovf[o] = v;
        }
    }
}

// ---------------- fused: row sort + quad bf16 gather + k-split matvecs -------
// one block per bucket (8 rows); 256 threads = 4 waves.
// gather: wave owns 2 rows, 4 edges per wave-iteration (16 lanes x uint4 each).
// matvec: wave owns a 32-wide k-slice of ALL rows; partials reduced via LDS.

__global__ __launch_bounds__(256) void k_fused(
        const uint32* __restrict__ xb, const int* __restrict__ bcur,
        const uint32* __restrict__ eb,
        const int* __restrict__ ovfn, const uint32* __restrict__ ovf,
        const uint32* __restrict__ WTmb, const float* __restrict__ bm,
        const uint32* __restrict__ WTub, const float* __restrict__ bu,
        float* __restrict__ out, int N_) {
    __shared__ float a_lds[RPB][D];          // 4 KB aggregated sums
    __shared__ float o_lds[RPB][D];          // 4 KB intermediate
    __shared__ float p_lds[4][RPB][D];       // 16 KB matvec partials (aliased)
    __shared__ int hist8[RPB], cur8[RPB], rst[RPB], dcnt[RPB];

    uint32* ebl = (uint32*)p_lds;            // [CAP]  4 KB  (sort phase only)
    uint16* stg = (uint16*)(ebl + CAP);      // [CAP]  2 KB  (sort+gather phase)

    const int tid  = threadIdx.x;
    const int lane = tid & 63;
    const int wv   = tid >> 6;

    for (int i = tid; i < RPB * D; i += 256) ((float*)a_lds)[i] = 0.f;
    if (tid < RPB) { hist8[tid] = 0; cur8[tid] = 0; }
    __syncthreads();

    const int ebase = blockIdx.x << 10;
    const int cnt   = bcur[blockIdx.x];
    const int cntc  = min(cnt, CAP);

    // pass A: cache edges in LDS + ballot row histogram
    {
        int cnt_loc = 0;
        for (int i0 = 0; i0 < cntc; i0 += 256) {
            int i = i0 + tid;
            bool valid = i < cntc;
            uint32 v = valid ? eb[ebase + i] : 0u;
            if (valid) ebl[i] = v;
            int myr = (v >> 16) & 7;
            #pragma unroll
            for (int r = 0; r < RPB; ++r) {
                unsigned long long m = __ballot(valid && (myr == r));
                if (lane == r) cnt_loc += __popcll(m);
            }
        }
        if (lane < RPB && cnt_loc) atomicAdd(&hist8[lane], cnt_loc);
    }
    __syncthreads();
    if (tid == 0) {
        int run = 0;
        #pragma unroll
        for (int r = 0; r < RPB; ++r) { rst[r] = run; run += hist8[r]; dcnt[r] = hist8[r]; }
    }
    __syncthreads();

    // pass B: scatter cols into row-sorted staging (from LDS)
    for (int i = tid; i < cntc; i += 256) {
        uint32 v = ebl[i];
        int r = (v >> 16) & 7;
        int p = rst[r] + atomicAdd(&cur8[r], 1);
        stg[p] = (uint16)(v & 0xffffu);
    }
    // overflow path (cnt > CAP: never taken in practice; correct + slow)
    if (cnt > CAP) {
        int no = min(*ovfn, OVFCAP);
        for (int ii = wv * 64; ii < no; ii += 256) {
            int m = min(64, no - ii);
            uint32 v_l = 0;
            if (lane < m) {
                v_l = ovf[ii + lane];
                if ((v_l >> 19) == (uint32)blockIdx.x)
                    atomicAdd(&dcnt[(v_l >> 16) & 7], 1);
            }
            for (int t = 0; t < m; ++t) {
                uint32 ev = __builtin_amdgcn_readlane(v_l, t);
                if ((ev >> 19) != (uint32)blockIdx.x) continue;
                uint32 v = xb[((ev & 0xffffu) << 6) + lane];
                int r = (ev >> 16) & 7;
                atomicAdd(&a_lds[r][lane],      bfl(v));
                atomicAdd(&a_lds[r][lane + 64], bfh(v));
            }
        }
    }
    __syncthreads();

    // ---- quad gather: wave owns rows {2wv, 2wv+1}; 4 edges per iteration ----
    // lane = 16*q + lf; lane loads xb4[c*16 + lf] = features
    // (4lf..4lf+3, 4lf+64..4lf+67) of its quarter's edge.
    const int q  = lane >> 4;
    const int lf = lane & 15;
    const uint4* __restrict__ xb4 = (const uint4*)xb;   // row = 16 uint4

    #pragma unroll
    for (int j = 0; j < 2; ++j) {
        int r  = wv * 2 + j;
        int lo = rst[r];
        int n  = hist8[r];
        int nq = n >> 2;

        float4 aL = make_float4(0.f, 0.f, 0.f, 0.f);
        float4 aH = make_float4(0.f, 0.f, 0.f, 0.f);

        int it = 0;
        for (; it + 2 <= nq; it += 2) {
            int cA = stg[lo + 4 * it + q];
            int cB = stg[lo + 4 * (it + 1) + q];
            uint4 vA = xb4[(cA << 4) + lf];
            uint4 vB = xb4[(cB << 4) + lf];
            aL.x += bfl(vA.x); aH.x += bfh(vA.x);
            aL.y += bfl(vA.y); aH.y += bfh(vA.y);
            aL.z += bfl(vA.z); aH.z += bfh(vA.z);
            aL.w += bfl(vA.w); aH.w += bfh(vA.w);
            aL.x += bfl(vB.x); aH.x += bfh(vB.x);
            aL.y += bfl(vB.y); aH.y += bfh(vB.y);
            aL.z += bfl(vB.z); aH.z += bfh(vB.z);
            aL.w += bfl(vB.w); aH.w += bfh(vB.w);
        }
        for (; it < nq; ++it) {
            int c = stg[lo + 4 * it + q];
            uint4 v = xb4[(c << 4) + lf];
            aL.x += bfl(v.x); aH.x += bfh(v.x);
            aL.y += bfl(v.y); aH.y += bfh(v.y);
            aL.z += bfl(v.z); aH.z += bfh(v.z);
            aL.w += bfl(v.w); aH.w += bfh(v.w);
        }
        int rem = n & 3;
        if (q < rem) {     // tail edges handled one per quarter
            int c = stg[lo + 4 * nq + q];
            uint4 v = xb4[(c << 4) + lf];
            aL.x += bfl(v.x); aH.x += bfh(v.x);
            aL.y += bfl(v.y); aH.y += bfh(v.y);
            aL.z += bfl(v.z); aH.z += bfh(v.z);
            aL.w += bfl(v.w); aH.w += bfh(v.w);
        }
        // combine quarters
        aL.x += __shfl_xor(aL.x, 16); aL.x += __shfl_xor(aL.x, 32);
        aL.y += __shfl_xor(aL.y, 16); aL.y += __shfl_xor(aL.y, 32);
        aL.z += __shfl_xor(aL.z, 16); aL.z += __shfl_xor(aL.z, 32);
        aL.w += __shfl_xor(aL.w, 16); aL.w += __shfl_xor(aL.w, 32);
        aH.x += __shfl_xor(aH.x, 16); aH.x += __shfl_xor(aH.x, 32);
        aH.y += __shfl_xor(aH.y, 16); aH.y += __shfl_xor(aH.y, 32);
        aH.z += __shfl_xor(aH.z, 16); aH.z += __shfl_xor(aH.z, 32);
        aH.w += __shfl_xor(aH.w, 16); aH.w += __shfl_xor(aH.w, 32);
        if (q == 0) {      // exclusive (row, lf) per lane: plain RMW
            float4 o0 = *(const float4*)&a_lds[r][4 * lf];
            float4 o1 = *(const float4*)&a_lds[r][4 * lf + 64];
            o0.x += aL.x; o0.y += aL.y; o0.z += aL.z; o0.w += aL.w;
            o1.x += aH.x; o1.y += aH.y; o1.z += aH.z; o1.w += aH.w;
            *(float4*)&a_lds[r][4 * lf]      = o0;
            *(float4*)&a_lds[r][4 * lf + 64] = o1;
        }
    }
    __syncthreads();

    // ---- matvec 1 (k-split): wave wv covers k in [32*wv, 32*wv+32), all rows
    const int f0 = lane, f1 = lane + 64;
    const int k0b = wv * 32;

    float acc0[RPB], acc1[RPB];
    #pragma unroll
    for (int r = 0; r < RPB; ++r) { acc0[r] = 0.f; acc1[r] = 0.f; }

    #pragma unroll
    for (int kk = 0; kk < 32; kk += 4) {
        int k2 = (k0b + kk) >> 1;
        uint32 wm00 = WTmb[k2 * D + f0];
        uint32 wm01 = WTmb[(k2 + 1) * D + f0];
        uint32 wm10 = WTmb[k2 * D + f1];
        uint32 wm11 = WTmb[(k2 + 1) * D + f1];
        float w00l = bfl(wm00), w00h = bfh(wm00), w01l = bfl(wm01), w01h = bfh(wm01);
        float w10l = bfl(wm10), w10h = bfh(wm10), w11l = bfl(wm11), w11h = bfh(wm11);
        #pragma unroll
        for (int r = 0; r < RPB; ++r) {
            float4 a4 = *(const float4*)&a_lds[r][k0b + kk];
            acc0[r] += a4.x * w00l + a4.y * w00h + a4.z * w01l + a4.w * w01h;
            acc1[r] += a4.x * w10l + a4.y * w10h + a4.z * w11l + a4.w * w11h;
        }
    }
    #pragma unroll
    for (int r = 0; r < RPB; ++r) {
        p_lds[wv][r][f0] = acc0[r];
        p_lds[wv][r][f1] = acc1[r];
    }
    __syncthreads();

    // ---- reduce 1 + bias + mean: thread -> (row, 4 features) ----
    {
        int r  = tid >> 5;
        int fq = (tid & 31) * 4;
        float4 s0 = *(const float4*)&p_lds[0][r][fq];
        float4 s1 = *(const float4*)&p_lds[1][r][fq];
        float4 s2 = *(const float4*)&p_lds[2][r][fq];
        float4 s3 = *(const float4*)&p_lds[3][r][fq];
        float cntf = (float)dcnt[r];
        float inv = 1.0f / (cntf + EPS);
        float4 b4 = *(const float4*)&bm[fq];
        float4 o;
        o.x = (s0.x + s1.x + s2.x + s3.x + cntf * b4.x) * inv;
        o.y = (s0.y + s1.y + s2.y + s3.y + cntf * b4.y) * inv;
        o.z = (s0.z + s1.z + s2.z + s3.z + cntf * b4.z) * inv;
        o.w = (s0.w + s1.w + s2.w + s3.w + cntf * b4.w) * inv;
        *(float4*)&o_lds[r][fq] = o;
    }
    __syncthreads();

    // ---- matvec 2 (k-split) ----
    #pragma unroll
    for (int r = 0; r < RPB; ++r) { acc0[r] = 0.f; acc1[r] = 0.f; }

    #pragma unroll
    for (int kk = 0; kk < 32; kk += 4) {
        int k2 = (k0b + kk) >> 1;
        uint32 wu00 = WTub[k2 * D + f0];
        uint32 wu01 = WTub[(k2 + 1) * D + f0];
        uint32 wu10 = WTub[k2 * D + f1];
        uint32 wu11 = WTub[(k2 + 1) * D + f1];
        float w00l = bfl(wu00), w00h = bfh(wu00), w01l = bfl(wu01), w01h = bfh(wu01);
        float w10l = bfl(wu10), w10h = bfh(wu10), w11l = bfl(wu11), w11h = bfh(wu11);
        #pragma unroll
        for (int r = 0; r < RPB; ++r) {
            float4 a4 = *(const float4*)&o_lds[r][k0b + kk];
            acc0[r] += a4.x * w00l + a4.y * w00h + a4.z * w01l + a4.w * w01h;
            acc1[r] += a4.x * w10l + a4.y * w10h + a4.z * w11l + a4.w * w11h;
        }
    }
    __syncthreads();   // reduce-1 reads of p_lds complete before rewrite
    #pragma unroll
    for (int r = 0; r < RPB; ++r) {
        p_lds[wv][r][f0] = acc0[r];
        p_lds[wv][r][f1] = acc1[r];
    }
    __syncthreads();

    // ---- reduce 2 + bias + row-norm + store ----
    {
        int r  = tid >> 5;
        int fq = (tid & 31) * 4;
        float4 s0 = *(const float4*)&p_lds[0][r][fq];
        float4 s1 = *(const float4*)&p_lds[1][r][fq];
        float4 s2 = *(const float4*)&p_lds[2][r][fq];
        float4 s3 = *(const float4*)&p_lds[3][r][fq];
        float4 b4 = *(const float4*)&bu[fq];
        float4 t;
        t.x = s0.x + s1.x + s2.x + s3.x + b4.x;
        t.y = s0.y + s1.y + s2.y + s3.y + b4.y;
        t.z = s0.z + s1.z + s2.z + s3.z + b4.z;
        t.w = s0.w + s1.w + s2.w + s3.w + b4.w;
        float ss = t.x * t.x + t.y * t.y + t.z * t.z + t.w * t.w;
        #pragma unroll
        for (int o = 16; o > 0; o >>= 1) ss += __shfl_xor(ss, o);
        float scale = 1.0f / (sqrtf(ss) + EPS);
        int n = blockIdx.x * RPB + r;
        if (n < N_) {
            float4 w;
            w.x = t.x * scale; w.y = t.y * scale; w.z = t.z * scale; w.w = t.w * scale;
            ((float4*)out)[n * 32 + (tid & 31)] = w;
        }
    }
}

// ---------------- launch ----------------

extern "C" void kernel_launch(void* const* d_in, const int* in_sizes, int n_in,
                              void* d_out, int out_size, void* d_ws, size_t ws_size,
                              hipStream_t stream) {
    const float* x  = (const float*)d_in[0];
    const int*   ei = (const int*)d_in[1];
    const float* Wm = (const float*)d_in[2];
    const float* bm = (const float*)d_in[3];
    const float* Wu = (const float*)d_in[4];
    const float* bu = (const float*)d_in[5];
    float* out = (float*)d_out;

    const int N_ = in_sizes[0] / D;        // 10000
    const int E_ = in_sizes[1] / 2;        // 640000
    const int NX = N_ * (D / 2);           // packed x pairs
    const int NB = (N_ + RPB - 1) / RPB;   // 1250 buckets

    uint32* xb   = (uint32*)d_ws;                 // NX          (16B aligned)
    uint32* eb   = xb + NX;                       // NB*CAP
    uint32* WTmb = eb + (size_t)NB * CAP;         // 64*128
    uint32* WTub = WTmb + 64 * D;                 // 64*128
    int*    bcur = (int*)(WTub + 64 * D);         // NB
    int*    ovfn = bcur + NB;                     // 1
    uint32* ovf  = (uint32*)(ovfn + 1);           // OVFCAP

    // zero bcur[NB] + ovfn with our own kernel: hipMemsetAsync's fill
    // dispatch costs ~40us in-graph (R12 rocprof), a kernel costs ~2us.
    k_zero<<<(NB + 1 + 255) / 256, 256, 0, stream>>>(bcur, NB + 1);

    const int nchunk = (E_ + EPB - 1) / EPB;          // 79
    const int npack  = (NX + 511) / 512;              // 1250
    k_stage<<<nchunk + npack, 512, 0, stream>>>(
        x, ei, Wm, Wu, xb, WTmb, WTub, bcur, ovfn, ovf, eb, E_, NX, NB, nchunk);

    k_fused<<<NB, 256, 0, stream>>>(xb, bcur, eb, ovfn, ovf,
                                    WTmb, bm, WTub, bu, out, N_);
}